// Round 9
// baseline (401.560 us; speedup 1.0000x reference)
//
#include <hip/hip_runtime.h>

typedef _Float16 h16;
typedef __attribute__((ext_vector_type(4))) _Float16 half4;
typedef __attribute__((ext_vector_type(8))) _Float16 half8;
typedef __attribute__((ext_vector_type(4))) float floatx4;
typedef __attribute__((ext_vector_type(16))) float floatx16;

__device__ __forceinline__ h16 f2h(float f){ return (h16)f; }
__device__ __forceinline__ float h2f(h16 s){ return (float)s; }

#define GL2LDS(gp, lp) __builtin_amdgcn_global_load_lds( \
    (const __attribute__((address_space(1))) void*)(gp), \
    (__attribute__((address_space(3))) void*)(lp), 16, 0, 0)

// ---- prep: z<4 -> weight transpose f32->f16 (64x64 tiles, vectorized);
//            z==4 -> hs f32->f16 (4x half8 per thread) --------------------
__global__ __launch_bounds__(256) void prep(const float* __restrict__ wq,
                                            const float* __restrict__ wk,
                                            const float* __restrict__ wv,
                                            const float* __restrict__ wo,
                                            const float* __restrict__ hs,
                                            h16* __restrict__ wqkv_t,
                                            h16* __restrict__ wo_t,
                                            h16* __restrict__ hs_f){
  __shared__ float tile[64][65];
  int z = blockIdx.z;
  int t = threadIdx.x;
  if (z == 4){
    int blk = (int)blockIdx.y*32 + (int)blockIdx.x;   // 1024 blocks
    for (int j=0;j<4;++j){
      int i = blk*1024 + j*256 + t;                   // half8 index
      floatx4 a = ((const floatx4*)hs)[2*i];
      floatx4 b = ((const floatx4*)hs)[2*i+1];
      half8 o;
      o[0]=f2h(a[0]); o[1]=f2h(a[1]); o[2]=f2h(a[2]); o[3]=f2h(a[3]);
      o[4]=f2h(b[0]); o[5]=f2h(b[1]); o[6]=f2h(b[2]); o[7]=f2h(b[3]);
      ((half8*)hs_f)[i] = o;
    }
    return;
  }
  const float* src = (z==0)? wq : (z==1)? wk : (z==2)? wv : wo;
  h16* dst = (z<3) ? (wqkv_t + (size_t)z*2048*2048) : wo_t;
  const int r0 = blockIdx.y*64, c0 = blockIdx.x*64;
  const int rr = t>>4, c4 = (t&15)*4;
  for (int p=0;p<4;++p){
    floatx4 v = *(const floatx4*)(src + (size_t)(r0+p*16+rr)*2048 + c0 + c4);
    tile[p*16+rr][c4+0]=v[0]; tile[p*16+rr][c4+1]=v[1];
    tile[p*16+rr][c4+2]=v[2]; tile[p*16+rr][c4+3]=v[3];
  }
  __syncthreads();
  const int rc = t&15;
  for (int p=0;p<4;++p){
    int cdst = (t>>4) + p*16;
    half4 o;
    o[0]=f2h(tile[rc*4+0][cdst]); o[1]=f2h(tile[rc*4+1][cdst]);
    o[2]=f2h(tile[rc*4+2][cdst]); o[3]=f2h(tile[rc*4+3][cdst]);
    *(half4*)(dst + (size_t)(c0+cdst)*2048 + r0 + rc*4) = o;
  }
}

// ---- fused QKV GEMM + rotary + head-split + V-transpose -----------------
// 128x128 tile, BK=64, XOR-swizzled GL2LDS staging, 32x32x16 MFMA.
__global__ __launch_bounds__(256) void gemm_qkv(const h16* __restrict__ A,
                                                const h16* __restrict__ Bt,
                                                h16* __restrict__ qT,
                                                h16* __restrict__ kT,
                                                h16* __restrict__ vT){
  const int K = 2048;
  __shared__ h16 smem[128*130];   // 33.3 KB: staging (32 KB) U epilogue tile
  h16* a_lds = smem;              // 128*64
  h16* b_lds = smem + 8192;       // 128*64
  const int t = threadIdx.x;
  const int m0 = blockIdx.y * 128, n0 = blockIdx.x * 128;
  const int wave = t >> 6, lane = t & 63;
  const int l32 = lane & 31, khalf = lane >> 5;
  const int wm = (wave & 1) * 64, wn = (wave >> 1) * 64;
  const int l3 = lane >> 3, c7 = lane & 7;
  const int xorc = c7 ^ l3;                    // global 16B chunk for this lane
  const h16* Ab = A  + (size_t)(m0 + wave*8 + l3)*K + xorc*8;
  const h16* Bb = Bt + (size_t)(n0 + wave*8 + l3)*K + xorc*8;
  h16* aL = a_lds + wave*512;
  h16* bL = b_lds + wave*512;

  floatx16 acc[2][2];
  for (int mi=0;mi<2;++mi) for (int ni=0;ni<2;++ni)
    for (int r=0;r<16;++r) acc[mi][ni][r] = 0.f;

  for (int k0 = 0; k0 < K; k0 += 64){
    for (int p=0;p<4;++p){
      GL2LDS(Ab + (size_t)p*32*K + k0, aL + p*2048);
      GL2LDS(Bb + (size_t)p*32*K + k0, bL + p*2048);
    }
    __syncthreads();
    for (int ks=0; ks<4; ++ks){
      const int s0 = ((ks*2 + khalf) ^ (l32 & 7)) * 8;
      half8 af[2], bfr[2];
      for (int mi=0;mi<2;++mi) af[mi]  = *(const half8*)(a_lds + (wm + mi*32 + l32)*64 + s0);
      for (int ni=0;ni<2;++ni) bfr[ni] = *(const half8*)(b_lds + (wn + ni*32 + l32)*64 + s0);
      for (int mi=0;mi<2;++mi)
        for (int ni=0;ni<2;++ni)
          acc[mi][ni] = __builtin_amdgcn_mfma_f32_32x32x16_f16(af[mi], bfr[ni], acc[mi][ni], 0,0,0);
    }
    __syncthreads();
  }
  // ---- epilogue: stage tile to LDS (stride 130 f16); 32x32 C/D layout:
  //      col = lane&31, row = (r&3) + 8*(r>>2) + 4*khalf [m74/m101]
  for (int mi=0;mi<2;++mi)
    for (int ni=0;ni<2;++ni)
      for (int r=0;r<16;++r){
        int rowl = (r&3) + 8*(r>>2) + 4*khalf;
        smem[(wm + mi*32 + rowl)*130 + wn + ni*32 + l32] = f2h(acc[mi][ni][r]);
      }
  __syncthreads();
  const int sec = n0 >> 11;           // 0=Q, 1=K, 2=V
  const int hh  = (n0 & 2047) >> 7;
  const int bb  = m0 >> 11;
  const int s0g = m0 & 2047;
  const int bhg = bb*16 + hh;
  if (sec < 2){
    h16* dst = sec ? kT : qT;
    const int d = t & 63;
    const int g = t >> 6;
    const float inv = __expf(-0.14391157f * (float)d);   // ln(10000)/64
    for (int p=0;p<32;++p){
      int sr = p*4 + g;
      int s  = s0g + sr;
      float sn, cs; __sincosf((float)s * inv, &sn, &cs);
      float x1 = h2f(smem[sr*130 + d]);
      float x2 = h2f(smem[sr*130 + d + 64]);
      size_t o = ((size_t)bhg*2048 + s)*128 + d;
      dst[o]      = f2h(x1*cs - x2*sn);
      dst[o + 64] = f2h(x2*cs + x1*sn);
    }
  } else {
    const int sr = t & 127;             // lane = s -> stride 65 words: conflict-free
    const int g  = t >> 7;
    for (int p=0;p<64;++p){
      int d = p*2 + g;
      vT[((size_t)bhg*128 + d)*2048 + s0g + sr] = smem[sr*130 + d];
    }
  }
}

// ---------------- O-projection GEMM: f32 out (BK=64, 32x32x16) -----------
__global__ __launch_bounds__(256) void gemm_out(const h16* __restrict__ A,
                                                const h16* __restrict__ Bt,
                                                float* __restrict__ Cout){
  const int K = 2048, N = 2048;
  __shared__ h16 a_lds[128*64];
  __shared__ h16 b_lds[128*64];
  const int t = threadIdx.x;
  const int m0 = blockIdx.y * 128, n0 = blockIdx.x * 128;
  const int wave = t >> 6, lane = t & 63;
  const int l32 = lane & 31, khalf = lane >> 5;
  const int wm = (wave & 1) * 64, wn = (wave >> 1) * 64;
  const int l3 = lane >> 3, c7 = lane & 7;
  const int xorc = c7 ^ l3;
  const h16* Ab = A  + (size_t)(m0 + wave*8 + l3)*K + xorc*8;
  const h16* Bb = Bt + (size_t)(n0 + wave*8 + l3)*K + xorc*8;
  h16* aL = a_lds + wave*512;
  h16* bL = b_lds + wave*512;

  floatx16 acc[2][2];
  for (int mi=0;mi<2;++mi) for (int ni=0;ni<2;++ni)
    for (int r=0;r<16;++r) acc[mi][ni][r] = 0.f;

  for (int k0 = 0; k0 < K; k0 += 64){
    for (int p=0;p<4;++p){
      GL2LDS(Ab + (size_t)p*32*K + k0, aL + p*2048);
      GL2LDS(Bb + (size_t)p*32*K + k0, bL + p*2048);
    }
    __syncthreads();
    for (int ks=0; ks<4; ++ks){
      const int s0 = ((ks*2 + khalf) ^ (l32 & 7)) * 8;
      half8 af[2], bfr[2];
      for (int mi=0;mi<2;++mi) af[mi]  = *(const half8*)(a_lds + (wm + mi*32 + l32)*64 + s0);
      for (int ni=0;ni<2;++ni) bfr[ni] = *(const half8*)(b_lds + (wn + ni*32 + l32)*64 + s0);
      for (int mi=0;mi<2;++mi)
        for (int ni=0;ni<2;++ni)
          acc[mi][ni] = __builtin_amdgcn_mfma_f32_32x32x16_f16(af[mi], bfr[ni], acc[mi][ni], 0,0,0);
    }
    __syncthreads();
  }
  for (int mi=0;mi<2;++mi)
    for (int ni=0;ni<2;++ni)
      for (int r=0;r<16;++r){
        int rowl = (r&3) + 8*(r>>2) + 4*khalf;
        Cout[(size_t)(m0 + wm + mi*32 + rowl)*N + n0 + wn + ni*32 + l32] = acc[mi][ni][r];
      }
}

// ---------------- flash attention (lingvo softmax + tanh cap) ------------
// Online softmax with running max (REQUIRED: P stored f16 for PV MFMA —
// fixed-m underflows f16; R6 lesson). MFMA row-sum via ones-rows.
// grid (16, h, b); block pairs q-tiles {x, 31-x} -> 33 kt per block.
__global__ __launch_bounds__(256) void flash_attn(const h16* __restrict__ qT,
                                                  const h16* __restrict__ kT,
                                                  const h16* __restrict__ vT,
                                                  h16* __restrict__ O){
  __shared__ h16 k_lds[64*136];    // [kn][kd], pad 128 -> 136
  __shared__ h16 v_lds[144*72];    // [d][s], rows 128..143 = ones
  __shared__ h16 p_lds[4*16*72];   // per-wave 16 x 64 (pad 72)
  const int t = threadIdx.x, wave = t>>6, lane = t&63, quad = lane>>4, l16 = lane&15;
  const int h = blockIdx.y, b = blockIdx.z;
  const int bh = b*16 + h;
  const int krow = t>>4, kch = t&15;
  const int vrow = t>>3, vch = t&7;
  const h16* kTb = kT + (size_t)bh*2048*128;
  const h16* vTb = vT + (size_t)bh*128*2048;
  floatx4 zero4 = {0.f,0.f,0.f,0.f};
  // ones rows for the MFMA row-sum trick
  for (int i = t; i < 16*64; i += 256)
    v_lds[(128 + (i>>6))*72 + (i&63)] = (h16)1.0f;
  __syncthreads();

  for (int half = 0; half < 2; ++half){
    const int qt = half ? 31 - (int)blockIdx.x : (int)blockIdx.x;
    const int q0 = qt*64;
    const size_t qrow = (size_t)bh*2048 + q0 + wave*16 + l16;
    half8 aq[4];
    for (int kc=0;kc<4;++kc) aq[kc] = *(const half8*)(qT + qrow*128 + kc*32 + quad*8);
    floatx4 acc_o[8];
    for (int nt=0;nt<8;++nt) acc_o[nt] = zero4;
    floatx4 acc_l = zero4;              // row-sum accumulator
    float mrow[4] = {0.f,0.f,0.f,0.f};  // lingvo: max clamped at 0

    half8 kreg[4], vreg[4];
    for (int p=0;p<4;++p){
      kreg[p] = *(const half8*)(kTb + (size_t)(p*16 + krow)*128 + kch*8);
      vreg[p] = *(const half8*)(vTb + (size_t)(p*32 + vrow)*2048 + vch*8);
    }

    for (int kt = 0; kt <= qt; ++kt){
      const int kbase = kt*64;
      __syncthreads();
      for (int p=0;p<4;++p){
        *(half8*)(k_lds + (p*16 + krow)*136 + kch*8) = kreg[p];
        *(half8*)(v_lds + (p*32 + vrow)*72  + vch*8) = vreg[p];
      }
      __syncthreads();
      if (kt < qt){
        const int nb = kbase + 64;
        for (int p=0;p<4;++p){
          kreg[p] = *(const half8*)(kTb + (size_t)(nb + p*16 + krow)*128 + kch*8);
          vreg[p] = *(const half8*)(vTb + (size_t)(p*32 + vrow)*2048 + nb + vch*8);
        }
      }
      floatx4 s[4];
      for (int ni=0;ni<4;++ni){
        floatx4 a = zero4;
        for (int kc=0;kc<4;++kc){
          half8 bk = *(const half8*)(k_lds + (ni*16 + l16)*136 + kc*32 + quad*8);
          a = __builtin_amdgcn_mfma_f32_16x16x32_f16(aq[kc], bk, a, 0,0,0);
        }
        s[ni] = a;
      }
      float pm[4][4];
      float tmax[4] = {-1e30f,-1e30f,-1e30f,-1e30f};
      const bool diag = (kt == qt);
      for (int ni=0;ni<4;++ni){
        int col = kbase + ni*16 + l16;
        for (int r=0;r<4;++r){
          float e = __expf(s[ni][r] * 0.04f);          // 50*tanh(x/50)
          float x = 50.f - 100.f * __builtin_amdgcn_rcpf(e + 1.f);
          if (diag){
            int row = q0 + wave*16 + quad*4 + r;
            if (col > row) x = -1e30f;
          }
          pm[ni][r] = x;
          tmax[r] = fmaxf(tmax[r], x);
        }
      }
      for (int r=0;r<4;++r)
        for (int off=1; off<16; off<<=1)
          tmax[r] = fmaxf(tmax[r], __shfl_xor(tmax[r], off, 16));
      float alpha[4], mnew[4];
      for (int r=0;r<4;++r){
        mnew[r] = fmaxf(mrow[r], tmax[r]);
        alpha[r] = __expf(mrow[r] - mnew[r]);
        mrow[r] = mnew[r];
      }
      for (int ni=0;ni<4;++ni)
        for (int r=0;r<4;++r)
          pm[ni][r] = __expf(pm[ni][r] - mnew[r]);
      for (int nt=0;nt<8;++nt)
        for (int r=0;r<4;++r) acc_o[nt][r] *= alpha[r];
      for (int r=0;r<4;++r) acc_l[r] *= alpha[r];
      h16* pw = p_lds + wave*16*72;
      for (int ni=0;ni<4;++ni)
        for (int r=0;r<4;++r)
          pw[(quad*4+r)*72 + ni*16 + l16] = f2h(pm[ni][r]);
      __builtin_amdgcn_wave_barrier();
      half8 ap0 = *(const half8*)(pw + l16*72 + quad*8);
      half8 ap1 = *(const half8*)(pw + l16*72 + 32 + quad*8);
      for (int nt=0;nt<8;++nt){
        half8 bv0 = *(const half8*)(v_lds + (nt*16 + l16)*72 + quad*8);
        half8 bv1 = *(const half8*)(v_lds + (nt*16 + l16)*72 + 32 + quad*8);
        acc_o[nt] = __builtin_amdgcn_mfma_f32_16x16x32_f16(ap0, bv0, acc_o[nt], 0,0,0);
        acc_o[nt] = __builtin_amdgcn_mfma_f32_16x16x32_f16(ap1, bv1, acc_o[nt], 0,0,0);
      }
      { // row-sum via ones rows 128..143
        half8 bo0 = *(const half8*)(v_lds + (128 + l16)*72 + quad*8);
        half8 bo1 = *(const half8*)(v_lds + (128 + l16)*72 + 32 + quad*8);
        acc_l = __builtin_amdgcn_mfma_f32_16x16x32_f16(ap0, bo0, acc_l, 0,0,0);
        acc_l = __builtin_amdgcn_mfma_f32_16x16x32_f16(ap1, bo1, acc_l, 0,0,0);
      }
    }
    float invl[4];
    for (int r=0;r<4;++r) invl[r] = 1.0f / (acc_l[r] + __expf(-mrow[r]));
    for (int nt=0;nt<8;++nt)
      for (int r=0;r<4;++r){
        int row = q0 + wave*16 + quad*4 + r;
        int col = h*128 + nt*16 + l16;
        O[((size_t)b*2048 + row)*2048 + col] = f2h(acc_o[nt][r] * invl[r]);
      }
  }
}

extern "C" void kernel_launch(void* const* d_in, const int* in_sizes, int n_in,
                              void* d_out, int out_size, void* d_ws, size_t ws_size,
                              hipStream_t stream){
  (void)in_sizes; (void)n_in; (void)out_size; (void)ws_size;
  const float* hs = (const float*)d_in[0];
  const float* wq = (const float*)d_in[1];
  const float* wk = (const float*)d_in[2];
  const float* wv = (const float*)d_in[3];
  const float* wo = (const float*)d_in[4];

  char* ws = (char*)d_ws;
  size_t off = 0;
  h16* hs_f   = (h16*)(ws + off); off += (size_t)4096*2048*2;
  h16* wqkv_t = (h16*)(ws + off); off += (size_t)6144*2048*2;
  h16* wo_t   = (h16*)(ws + off); off += (size_t)2048*2048*2;
  h16* qT     = (h16*)(ws + off); off += (size_t)4096*2048*2;
  h16* kT     = (h16*)(ws + off); off += (size_t)4096*2048*2;
  h16* vT     = (h16*)(ws + off); off += (size_t)4096*2048*2;
  h16* obuf   = (h16*)(ws + off); off += (size_t)4096*2048*2;

  prep<<<dim3(32,32,5), 256, 0, stream>>>(wq, wk, wv, wo, hs, wqkv_t, wo_t, hs_f);
  gemm_qkv<<<dim3(48,32), 256, 0, stream>>>(hs_f, wqkv_t, qT, kT, vT);
  flash_attn<<<dim3(16,16,2), 256, 0, stream>>>(qT, kT, vT, obuf);
  gemm_out<<<dim3(16,32), 256, 0, stream>>>(obuf, wo_t, (float*)d_out);
}

// Round 10
// 401.496 us; speedup vs baseline: 1.0002x; 1.0002x over previous
//
#include <hip/hip_runtime.h>

typedef _Float16 h16;
typedef __attribute__((ext_vector_type(4))) _Float16 half4;
typedef __attribute__((ext_vector_type(8))) _Float16 half8;
typedef __attribute__((ext_vector_type(4))) float floatx4;
typedef __attribute__((ext_vector_type(16))) float floatx16;

__device__ __forceinline__ h16 f2h(float f){ return (h16)f; }
__device__ __forceinline__ float h2f(h16 s){ return (float)s; }

#define GL2LDS(gp, lp) __builtin_amdgcn_global_load_lds( \
    (const __attribute__((address_space(1))) void*)(gp), \
    (__attribute__((address_space(3))) void*)(lp), 16, 0, 0)

// ---- prep: z<4 -> weight transpose f32->f16 (64x64 tiles, vectorized);
//            z==4 -> hs f32->f16 (4x half8 per thread) --------------------
__global__ __launch_bounds__(256) void prep(const float* __restrict__ wq,
                                            const float* __restrict__ wk,
                                            const float* __restrict__ wv,
                                            const float* __restrict__ wo,
                                            const float* __restrict__ hs,
                                            h16* __restrict__ wqkv_t,
                                            h16* __restrict__ wo_t,
                                            h16* __restrict__ hs_f){
  __shared__ float tile[64][65];
  int z = blockIdx.z;
  int t = threadIdx.x;
  if (z == 4){
    int blk = (int)blockIdx.y*32 + (int)blockIdx.x;   // 1024 blocks
    for (int j=0;j<4;++j){
      int i = blk*1024 + j*256 + t;                   // half8 index
      floatx4 a = ((const floatx4*)hs)[2*i];
      floatx4 b = ((const floatx4*)hs)[2*i+1];
      half8 o;
      o[0]=f2h(a[0]); o[1]=f2h(a[1]); o[2]=f2h(a[2]); o[3]=f2h(a[3]);
      o[4]=f2h(b[0]); o[5]=f2h(b[1]); o[6]=f2h(b[2]); o[7]=f2h(b[3]);
      ((half8*)hs_f)[i] = o;
    }
    return;
  }
  const float* src = (z==0)? wq : (z==1)? wk : (z==2)? wv : wo;
  h16* dst = (z<3) ? (wqkv_t + (size_t)z*2048*2048) : wo_t;
  const int r0 = blockIdx.y*64, c0 = blockIdx.x*64;
  const int rr = t>>4, c4 = (t&15)*4;
  for (int p=0;p<4;++p){
    floatx4 v = *(const floatx4*)(src + (size_t)(r0+p*16+rr)*2048 + c0 + c4);
    tile[p*16+rr][c4+0]=v[0]; tile[p*16+rr][c4+1]=v[1];
    tile[p*16+rr][c4+2]=v[2]; tile[p*16+rr][c4+3]=v[3];
  }
  __syncthreads();
  const int rc = t&15;
  for (int p=0;p<4;++p){
    int cdst = (t>>4) + p*16;
    half4 o;
    o[0]=f2h(tile[rc*4+0][cdst]); o[1]=f2h(tile[rc*4+1][cdst]);
    o[2]=f2h(tile[rc*4+2][cdst]); o[3]=f2h(tile[rc*4+3][cdst]);
    *(half4*)(dst + (size_t)(c0+cdst)*2048 + r0 + rc*4) = o;
  }
}

// ---- fused QKV GEMM + rotary + head-split + V-transpose -----------------
// 128x128 tile, BK=64, XOR-swizzled GL2LDS staging, 32x32x16 MFMA.
__global__ __launch_bounds__(256) void gemm_qkv(const h16* __restrict__ A,
                                                const h16* __restrict__ Bt,
                                                h16* __restrict__ qT,
                                                h16* __restrict__ kT,
                                                h16* __restrict__ vT){
  const int K = 2048;
  __shared__ h16 smem[128*130];   // 33.3 KB: staging (32 KB) U epilogue tile
  h16* a_lds = smem;              // 128*64
  h16* b_lds = smem + 8192;       // 128*64
  const int t = threadIdx.x;
  const int m0 = blockIdx.y * 128, n0 = blockIdx.x * 128;
  const int wave = t >> 6, lane = t & 63;
  const int l32 = lane & 31, khalf = lane >> 5;
  const int wm = (wave & 1) * 64, wn = (wave >> 1) * 64;
  const int l3 = lane >> 3, c7 = lane & 7;
  const int xorc = c7 ^ l3;                    // global 16B chunk for this lane
  const h16* Ab = A  + (size_t)(m0 + wave*8 + l3)*K + xorc*8;
  const h16* Bb = Bt + (size_t)(n0 + wave*8 + l3)*K + xorc*8;
  h16* aL = a_lds + wave*512;
  h16* bL = b_lds + wave*512;

  floatx16 acc[2][2];
  for (int mi=0;mi<2;++mi) for (int ni=0;ni<2;++ni)
    for (int r=0;r<16;++r) acc[mi][ni][r] = 0.f;

  for (int k0 = 0; k0 < K; k0 += 64){
    for (int p=0;p<4;++p){
      GL2LDS(Ab + (size_t)p*32*K + k0, aL + p*2048);
      GL2LDS(Bb + (size_t)p*32*K + k0, bL + p*2048);
    }
    __syncthreads();
    for (int ks=0; ks<4; ++ks){
      const int s0 = ((ks*2 + khalf) ^ (l32 & 7)) * 8;
      half8 af[2], bfr[2];
      for (int mi=0;mi<2;++mi) af[mi]  = *(const half8*)(a_lds + (wm + mi*32 + l32)*64 + s0);
      for (int ni=0;ni<2;++ni) bfr[ni] = *(const half8*)(b_lds + (wn + ni*32 + l32)*64 + s0);
      for (int mi=0;mi<2;++mi)
        for (int ni=0;ni<2;++ni)
          acc[mi][ni] = __builtin_amdgcn_mfma_f32_32x32x16_f16(af[mi], bfr[ni], acc[mi][ni], 0,0,0);
    }
    __syncthreads();
  }
  // ---- epilogue: stage tile to LDS (stride 130 f16); 32x32 C/D layout:
  //      col = lane&31, row = (r&3) + 8*(r>>2) + 4*khalf [m74/m101]
  for (int mi=0;mi<2;++mi)
    for (int ni=0;ni<2;++ni)
      for (int r=0;r<16;++r){
        int rowl = (r&3) + 8*(r>>2) + 4*khalf;
        smem[(wm + mi*32 + rowl)*130 + wn + ni*32 + l32] = f2h(acc[mi][ni][r]);
      }
  __syncthreads();
  const int sec = n0 >> 11;           // 0=Q, 1=K, 2=V
  const int hh  = (n0 & 2047) >> 7;
  const int bb  = m0 >> 11;
  const int s0g = m0 & 2047;
  const int bhg = bb*16 + hh;
  if (sec < 2){
    h16* dst = sec ? kT : qT;
    const int d = t & 63;
    const int g = t >> 6;
    const float inv = __expf(-0.14391157f * (float)d);   // ln(10000)/64
    for (int p=0;p<32;++p){
      int sr = p*4 + g;
      int s  = s0g + sr;
      float sn, cs; __sincosf((float)s * inv, &sn, &cs);
      float x1 = h2f(smem[sr*130 + d]);
      float x2 = h2f(smem[sr*130 + d + 64]);
      size_t o = ((size_t)bhg*2048 + s)*128 + d;
      dst[o]      = f2h(x1*cs - x2*sn);
      dst[o + 64] = f2h(x2*cs + x1*sn);
    }
  } else {
    const int sr = t & 127;             // lane = s -> stride 65 words: conflict-free
    const int g  = t >> 7;
    for (int p=0;p<64;++p){
      int d = p*2 + g;
      vT[((size_t)bhg*128 + d)*2048 + s0g + sr] = smem[sr*130 + d];
    }
  }
}

// ---------------- O-projection GEMM: f32 out (BK=64, 32x32x16) -----------
__global__ __launch_bounds__(256) void gemm_out(const h16* __restrict__ A,
                                                const h16* __restrict__ Bt,
                                                float* __restrict__ Cout){
  const int K = 2048, N = 2048;
  __shared__ h16 a_lds[128*64];
  __shared__ h16 b_lds[128*64];
  const int t = threadIdx.x;
  const int m0 = blockIdx.y * 128, n0 = blockIdx.x * 128;
  const int wave = t >> 6, lane = t & 63;
  const int l32 = lane & 31, khalf = lane >> 5;
  const int wm = (wave & 1) * 64, wn = (wave >> 1) * 64;
  const int l3 = lane >> 3, c7 = lane & 7;
  const int xorc = c7 ^ l3;
  const h16* Ab = A  + (size_t)(m0 + wave*8 + l3)*K + xorc*8;
  const h16* Bb = Bt + (size_t)(n0 + wave*8 + l3)*K + xorc*8;
  h16* aL = a_lds + wave*512;
  h16* bL = b_lds + wave*512;

  floatx16 acc[2][2];
  for (int mi=0;mi<2;++mi) for (int ni=0;ni<2;++ni)
    for (int r=0;r<16;++r) acc[mi][ni][r] = 0.f;

  for (int k0 = 0; k0 < K; k0 += 64){
    for (int p=0;p<4;++p){
      GL2LDS(Ab + (size_t)p*32*K + k0, aL + p*2048);
      GL2LDS(Bb + (size_t)p*32*K + k0, bL + p*2048);
    }
    __syncthreads();
    for (int ks=0; ks<4; ++ks){
      const int s0 = ((ks*2 + khalf) ^ (l32 & 7)) * 8;
      half8 af[2], bfr[2];
      for (int mi=0;mi<2;++mi) af[mi]  = *(const half8*)(a_lds + (wm + mi*32 + l32)*64 + s0);
      for (int ni=0;ni<2;++ni) bfr[ni] = *(const half8*)(b_lds + (wn + ni*32 + l32)*64 + s0);
      for (int mi=0;mi<2;++mi)
        for (int ni=0;ni<2;++ni)
          acc[mi][ni] = __builtin_amdgcn_mfma_f32_32x32x16_f16(af[mi], bfr[ni], acc[mi][ni], 0,0,0);
    }
    __syncthreads();
  }
  for (int mi=0;mi<2;++mi)
    for (int ni=0;ni<2;++ni)
      for (int r=0;r<16;++r){
        int rowl = (r&3) + 8*(r>>2) + 4*khalf;
        Cout[(size_t)(m0 + wm + mi*32 + rowl)*N + n0 + wn + ni*32 + l32] = acc[mi][ni][r];
      }
}

// ---------------- flash attention (lingvo softmax + tanh cap) ------------
// 128-row Q-tiles, 512 thr = 8 waves x 16 q-rows: K/V staging + barriers
// amortized 2x vs 64-row blocks. grid (8, 16, 2); block pairs q-tiles
// {x, 15-x} -> 34 kt per block (balanced); 256 blocks = 1/CU, 2 waves/SIMD.
// Online softmax (P stored f16 -> running max REQUIRED; R6 lesson).
__global__ __launch_bounds__(512) void flash_attn(const h16* __restrict__ qT,
                                                  const h16* __restrict__ kT,
                                                  const h16* __restrict__ vT,
                                                  h16* __restrict__ O){
  __shared__ h16 k_lds[64*136];    // [kn][kd], pad 128 -> 136
  __shared__ h16 v_lds[144*72];    // [d][s], rows 128..143 = ones
  __shared__ h16 p_lds[8*16*72];   // per-wave 16 x 64 (pad 72)
  const int t = threadIdx.x, wave = t>>6, lane = t&63, quad = lane>>4, l16 = lane&15;
  const int h = blockIdx.y, b = blockIdx.z;
  const int bh = b*16 + h;
  const int krow = t>>4, kch = t&15;     // K: rows krow, krow+32  (512 thr)
  const int vrow = t>>3, vch = t&7;      // V: d = vrow, vrow+64
  const h16* kTb = kT + (size_t)bh*2048*128;
  const h16* vTb = vT + (size_t)bh*128*2048;
  floatx4 zero4 = {0.f,0.f,0.f,0.f};
  // ones rows for the MFMA row-sum trick
  for (int i = t; i < 16*64; i += 512)
    v_lds[(128 + (i>>6))*72 + (i&63)] = (h16)1.0f;
  __syncthreads();

  for (int half = 0; half < 2; ++half){
    const int qt = half ? 15 - (int)blockIdx.x : (int)blockIdx.x;  // 0..15
    const int q0 = qt*128;
    const int qr0 = q0 + wave*16;        // this wave's 16 q-rows
    const size_t qrow = (size_t)bh*2048 + qr0 + l16;
    half8 aq[4];
    for (int kc=0;kc<4;++kc) aq[kc] = *(const half8*)(qT + qrow*128 + kc*32 + quad*8);
    floatx4 acc_o[8];
    for (int nt=0;nt<8;++nt) acc_o[nt] = zero4;
    floatx4 acc_l = zero4;              // row-sum accumulator
    float mrow[4] = {0.f,0.f,0.f,0.f};  // lingvo: max clamped at 0

    half8 kreg[2], vreg[2];
    for (int p=0;p<2;++p){
      kreg[p] = *(const half8*)(kTb + (size_t)(p*32 + krow)*128 + kch*8);
      vreg[p] = *(const half8*)(vTb + (size_t)(p*64 + vrow)*2048 + vch*8);
    }

    const int ktmax = 2*qt + 1;
    for (int kt = 0; kt <= ktmax; ++kt){
      const int kbase = kt*64;
      __syncthreads();
      for (int p=0;p<2;++p){
        *(half8*)(k_lds + (p*32 + krow)*136 + kch*8) = kreg[p];
        *(half8*)(v_lds + (p*64 + vrow)*72  + vch*8) = vreg[p];
      }
      __syncthreads();
      if (kt < ktmax){
        const int nb = kbase + 64;
        for (int p=0;p<2;++p){
          kreg[p] = *(const half8*)(kTb + (size_t)(nb + p*32 + krow)*128 + kch*8);
          vreg[p] = *(const half8*)(vTb + (size_t)(p*64 + vrow)*2048 + nb + vch*8);
        }
      }
      floatx4 s[4];
      for (int ni=0;ni<4;++ni){
        floatx4 a = zero4;
        for (int kc=0;kc<4;++kc){
          half8 bk = *(const half8*)(k_lds + (ni*16 + l16)*136 + kc*32 + quad*8);
          a = __builtin_amdgcn_mfma_f32_16x16x32_f16(aq[kc], bk, a, 0,0,0);
        }
        s[ni] = a;
      }
      float pm[4][4];
      float tmax[4] = {-1e30f,-1e30f,-1e30f,-1e30f};
      const bool diag = (kbase + 63 > qr0);   // wave-level causal boundary
      for (int ni=0;ni<4;++ni){
        int col = kbase + ni*16 + l16;
        for (int r=0;r<4;++r){
          float e = __expf(s[ni][r] * 0.04f);          // 50*tanh(x/50)
          float x = 50.f - 100.f * __builtin_amdgcn_rcpf(e + 1.f);
          if (diag){
            int row = qr0 + quad*4 + r;
            if (col > row) x = -1e30f;
          }
          pm[ni][r] = x;
          tmax[r] = fmaxf(tmax[r], x);
        }
      }
      for (int r=0;r<4;++r)
        for (int off=1; off<16; off<<=1)
          tmax[r] = fmaxf(tmax[r], __shfl_xor(tmax[r], off, 16));
      float alpha[4], mnew[4];
      for (int r=0;r<4;++r){
        mnew[r] = fmaxf(mrow[r], tmax[r]);
        alpha[r] = __expf(mrow[r] - mnew[r]);
        mrow[r] = mnew[r];
      }
      for (int ni=0;ni<4;++ni)
        for (int r=0;r<4;++r)
          pm[ni][r] = __expf(pm[ni][r] - mnew[r]);
      for (int nt=0;nt<8;++nt)
        for (int r=0;r<4;++r) acc_o[nt][r] *= alpha[r];
      for (int r=0;r<4;++r) acc_l[r] *= alpha[r];
      h16* pw = p_lds + wave*16*72;
      for (int ni=0;ni<4;++ni)
        for (int r=0;r<4;++r)
          pw[(quad*4+r)*72 + ni*16 + l16] = f2h(pm[ni][r]);
      __builtin_amdgcn_wave_barrier();
      half8 ap0 = *(const half8*)(pw + l16*72 + quad*8);
      half8 ap1 = *(const half8*)(pw + l16*72 + 32 + quad*8);
      for (int nt=0;nt<8;++nt){
        half8 bv0 = *(const half8*)(v_lds + (nt*16 + l16)*72 + quad*8);
        half8 bv1 = *(const half8*)(v_lds + (nt*16 + l16)*72 + 32 + quad*8);
        acc_o[nt] = __builtin_amdgcn_mfma_f32_16x16x32_f16(ap0, bv0, acc_o[nt], 0,0,0);
        acc_o[nt] = __builtin_amdgcn_mfma_f32_16x16x32_f16(ap1, bv1, acc_o[nt], 0,0,0);
      }
      { // row-sum via ones rows 128..143
        half8 bo0 = *(const half8*)(v_lds + (128 + l16)*72 + quad*8);
        half8 bo1 = *(const half8*)(v_lds + (128 + l16)*72 + 32 + quad*8);
        acc_l = __builtin_amdgcn_mfma_f32_16x16x32_f16(ap0, bo0, acc_l, 0,0,0);
        acc_l = __builtin_amdgcn_mfma_f32_16x16x32_f16(ap1, bo1, acc_l, 0,0,0);
      }
    }
    float invl[4];
    for (int r=0;r<4;++r) invl[r] = 1.0f / (acc_l[r] + __expf(-mrow[r]));
    for (int nt=0;nt<8;++nt)
      for (int r=0;r<4;++r){
        int row = qr0 + quad*4 + r;
        int col = h*128 + nt*16 + l16;
        O[((size_t)b*2048 + row)*2048 + col] = f2h(acc_o[nt][r] * invl[r]);
      }
  }
}

extern "C" void kernel_launch(void* const* d_in, const int* in_sizes, int n_in,
                              void* d_out, int out_size, void* d_ws, size_t ws_size,
                              hipStream_t stream){
  (void)in_sizes; (void)n_in; (void)out_size; (void)ws_size;
  const float* hs = (const float*)d_in[0];
  const float* wq = (const float*)d_in[1];
  const float* wk = (const float*)d_in[2];
  const float* wv = (const float*)d_in[3];
  const float* wo = (const float*)d_in[4];

  char* ws = (char*)d_ws;
  size_t off = 0;
  h16* hs_f   = (h16*)(ws + off); off += (size_t)4096*2048*2;
  h16* wqkv_t = (h16*)(ws + off); off += (size_t)6144*2048*2;
  h16* wo_t   = (h16*)(ws + off); off += (size_t)2048*2048*2;
  h16* qT     = (h16*)(ws + off); off += (size_t)4096*2048*2;
  h16* kT     = (h16*)(ws + off); off += (size_t)4096*2048*2;
  h16* vT     = (h16*)(ws + off); off += (size_t)4096*2048*2;
  h16* obuf   = (h16*)(ws + off); off += (size_t)4096*2048*2;

  prep<<<dim3(32,32,5), 256, 0, stream>>>(wq, wk, wv, wo, hs, wqkv_t, wo_t, hs_f);
  gemm_qkv<<<dim3(48,32), 256, 0, stream>>>(hs_f, wqkv_t, qT, kT, vT);
  flash_attn<<<dim3(8,16,2), 512, 0, stream>>>(qT, kT, vT, obuf);
  gemm_out<<<dim3(16,32), 256, 0, stream>>>(obuf, wo_t, (float*)d_out);
}